// Round 2
// baseline (22332.480 us; speedup 1.0000x reference)
//
#include <hip/hip_runtime.h>
#include <stdint.h>

// SRTKAN: 2-layer GRU scan (T=512) -> 2x bidirectional single-step LSTM -> 2x KAN linear.
// Input dtype (fp32 vs bf16) detected ON DEVICE each launch (flag in d_ws); weights are
// staged as bf16 in d_ws; GRU x-loads and final output writes are dual-path on the flag.
// fp32 internal math, MFMA bf16 for GRU GEMMs.

constexpr int B_  = 512;
constexpr int T_  = 512;
constexpr int IN_ = 128;
constexpr int H_  = 256;
constexpr int HP_ = 264;   // padded bf16 row stride for h tiles in LDS

typedef __attribute__((ext_vector_type(8))) short bf16x8;
typedef __attribute__((ext_vector_type(4))) float f32x4;

#define MFMA16(a, b, c) __builtin_amdgcn_mfma_f32_16x16x32_bf16((a), (b), (c), 0, 0, 0)

__device__ __forceinline__ float bf2f(unsigned short u){
    union { unsigned int i; float f; } v; v.i = ((unsigned int)u) << 16; return v.f;
}
__device__ __forceinline__ unsigned short f2bf(float f){
    union { float f; unsigned int i; } v; v.f = f;
    return (unsigned short)((v.i + 0x7FFFu + ((v.i >> 16) & 1u)) >> 16); // RNE
}
__device__ __forceinline__ float sig_(float x){
    return __builtin_amdgcn_rcpf(1.0f + __expf(-x));
}
__device__ __forceinline__ float tanh_(float x){
    return 1.0f - 2.0f * __builtin_amdgcn_rcpf(1.0f + __expf(2.0f * x));
}
__device__ __forceinline__ bf16x8 ldb8g(const unsigned short* p){ return *(const bf16x8*)p; }

// ---------------------------------------------------------------------------
// dtype detect: low 16 bits of fp32 words of x. bf16-packed -> those are real bf16
// values of ~N(0,1) data (exponent 100..140 essentially always). fp32 data -> uniform
// mantissa bits (~16% in window). One wave, 1024 words.
// ---------------------------------------------------------------------------
__global__ void srt_detect(const unsigned int* __restrict__ xw, unsigned int* __restrict__ flag){
    int cnt = 0;
    for (int i = threadIdx.x; i < 1024; i += 64){
        const unsigned int lo = xw[i] & 0xFFFFu;
        const int e = (int)((lo >> 7) & 0xFFu);
        if (e >= 100 && e <= 140) cnt++;
    }
    #pragma unroll
    for (int o = 32; o > 0; o >>= 1) cnt += __shfl_down(cnt, o);
    if (threadIdx.x == 0) *flag = (cnt > 614) ? 1u : 0u;   // 1 = bf16 inputs
}

// ---------------------------------------------------------------------------
// stage all weight/bias tensors as bf16 into d_ws (copy if bf16, RNE-convert if fp32)
// ---------------------------------------------------------------------------
struct ConvTab { const void* src[26]; int n[26]; int off[26]; };

__global__ __launch_bounds__(256) void srt_conv(ConvTab ct, unsigned short* __restrict__ wb,
                                                const unsigned int* __restrict__ flag){
    const bool isb = (*flag != 0);
    const int gsz = gridDim.x * blockDim.x;
    const int gid = blockIdx.x * blockDim.x + threadIdx.x;
    for (int j = 0; j < 26; ++j){
        const int n = ct.n[j];
        unsigned short* o = wb + ct.off[j];
        if (isb){
            const unsigned short* s = (const unsigned short*)ct.src[j];
            for (int i = gid; i < n; i += gsz) o[i] = s[i];
        } else {
            const float* s = (const float*)ct.src[j];
            for (int i = gid; i < n; i += gsz) o[i] = f2bf(s[i]);
        }
    }
}

// ---------------------------------------------------------------------------
// GRU persistent kernel: grid = 32, block = 256 (4 waves). Wave w owns features
// [w*64, w*64+64) as 4 feature-tiles of 16; block owns batch rows [bid*16, +16).
// MFMA 16x16x32 bf16; A[m=lane&15][k=quad*8+j]; B[k][n=lane&15]; C/D row=quad*4+reg.
// ---------------------------------------------------------------------------
__global__ __launch_bounds__(256, 1) void srt_gru(
    const void* __restrict__ xv,              // (B,T,IN) bf16 OR fp32 per flag
    const unsigned short* __restrict__ w0ih,  // (768,128) bf16 (ws copy)
    const unsigned short* __restrict__ w0hh,  // (768,256)
    const unsigned short* __restrict__ b0ih,  // (768)
    const unsigned short* __restrict__ b0hh,
    const unsigned short* __restrict__ w1ih,  // (768,256)
    const unsigned short* __restrict__ w1hh,  // (768,256)
    const unsigned short* __restrict__ b1ih,
    const unsigned short* __restrict__ b1hh,
    float* __restrict__ s_out,                // (B,H) fp32: final h1
    const unsigned int* __restrict__ flagp)
{
    __shared__ __align__(16) unsigned short h0b[16 * HP_];
    __shared__ __align__(16) unsigned short h1b[16 * HP_];
    __shared__ float brz0[512], bni0[256], bnh0[256];
    __shared__ float brz1[512], bni1[256], bnh1[256];

    const bool isb = (*flagp != 0);

    const int tid  = threadIdx.x;
    const int lane = tid & 63;
    const int wv   = tid >> 6;
    const int l15  = lane & 15;
    const int quad = lane >> 4;
    const int m0   = blockIdx.x * 16;
    const int fb0  = wv * 64;

    for (int i = tid; i < 16 * HP_; i += 256){ h0b[i] = 0; h1b[i] = 0; }
    for (int c = tid; c < 512; c += 256){
        brz0[c] = bf2f(b0ih[c]) + bf2f(b0hh[c]);
        brz1[c] = bf2f(b1ih[c]) + bf2f(b1hh[c]);
    }
    {
        const int c = tid; // block is exactly 256 threads
        bni0[c] = bf2f(b0ih[512 + c]); bnh0[c] = bf2f(b0hh[512 + c]);
        bni1[c] = bf2f(b1ih[512 + c]); bnh1[c] = bf2f(b1hh[512 + c]);
    }
    __syncthreads();

    float h0r[4][4], h1r[4][4];
    #pragma unroll
    for (int ft = 0; ft < 4; ++ft)
        #pragma unroll
        for (int j = 0; j < 4; ++j){ h0r[ft][j] = 0.f; h1r[ft][j] = 0.f; }

    int of_ih[4][3], of_hh[4][3];   // of_hh valid for w0hh / w1ih / w1hh (all 768x256)
    #pragma unroll
    for (int ft = 0; ft < 4; ++ft){
        const int fb = fb0 + ft * 16 + l15;
        #pragma unroll
        for (int g = 0; g < 3; ++g){
            of_ih[ft][g] = (g * 256 + fb) * IN_ + quad * 8;
            of_hh[ft][g] = (g * 256 + fb) * H_  + quad * 8;
        }
    }
    const size_t xrow = (size_t)(m0 + l15) * (T_ * IN_) + quad * 8;
    const unsigned short* pxb = (const unsigned short*)xv + xrow;
    const float*          pxf = (const float*)xv + xrow;
    const int hoff = l15 * HP_ + quad * 8;

    const f32x4 z4 = {0.f, 0.f, 0.f, 0.f};

    #pragma unroll 1
    for (int t = 0; t < T_; ++t){
        // ---- fetch x_t fragments (dual dtype path, uniform branch) ----
        bf16x8 ax[4];
        if (isb){
            #pragma unroll
            for (int kc = 0; kc < 4; ++kc) ax[kc] = ldb8g(pxb + t * IN_ + kc * 32);
        } else {
            #pragma unroll
            for (int kc = 0; kc < 4; ++kc){
                const float* p = pxf + t * IN_ + kc * 32;
                const float4 f0 = *(const float4*)p;
                const float4 f1 = *(const float4*)(p + 4);
                bf16x8 a;
                a[0] = (short)f2bf(f0.x); a[1] = (short)f2bf(f0.y);
                a[2] = (short)f2bf(f0.z); a[3] = (short)f2bf(f0.w);
                a[4] = (short)f2bf(f1.x); a[5] = (short)f2bf(f1.y);
                a[6] = (short)f2bf(f1.z); a[7] = (short)f2bf(f1.w);
                ax[kc] = a;
            }
        }

        f32x4 Tr[4]  = {z4, z4, z4, z4};
        f32x4 Tz[4]  = {z4, z4, z4, z4};
        f32x4 Tni[4] = {z4, z4, z4, z4};
        f32x4 Tnh[4] = {z4, z4, z4, z4};

        // ---- layer 0: x_t @ W0ih^T (K=128) ----
        #pragma unroll
        for (int kc = 0; kc < 4; ++kc){
            #pragma unroll
            for (int ft = 0; ft < 4; ++ft){
                Tr[ft]  = MFMA16(ax[kc], ldb8g(w0ih + of_ih[ft][0] + kc * 32), Tr[ft]);
                Tz[ft]  = MFMA16(ax[kc], ldb8g(w0ih + of_ih[ft][1] + kc * 32), Tz[ft]);
                Tni[ft] = MFMA16(ax[kc], ldb8g(w0ih + of_ih[ft][2] + kc * 32), Tni[ft]);
            }
        }
        // ---- layer 0: h0 @ W0hh^T (K=256) ----
        #pragma unroll
        for (int kc = 0; kc < 8; ++kc){
            const bf16x8 a = *(const bf16x8*)&h0b[hoff + kc * 32];
            #pragma unroll
            for (int ft = 0; ft < 4; ++ft){
                Tr[ft]  = MFMA16(a, ldb8g(w0hh + of_hh[ft][0] + kc * 32), Tr[ft]);
                Tz[ft]  = MFMA16(a, ldb8g(w0hh + of_hh[ft][1] + kc * 32), Tz[ft]);
                Tnh[ft] = MFMA16(a, ldb8g(w0hh + of_hh[ft][2] + kc * 32), Tnh[ft]);
            }
        }
        // ---- layer 0 gates ----
        #pragma unroll
        for (int ft = 0; ft < 4; ++ft){
            const int c = fb0 + ft * 16 + l15;
            #pragma unroll
            for (int j = 0; j < 4; ++j){
                const float rr = sig_(Tr[ft][j] + brz0[c]);
                const float zz = sig_(Tz[ft][j] + brz0[256 + c]);
                const float nn = tanh_(Tni[ft][j] + bni0[c] + rr * (Tnh[ft][j] + bnh0[c]));
                h0r[ft][j] = (1.0f - zz) * nn + zz * h0r[ft][j];
            }
        }
        __syncthreads();   // all waves done reading h0b (v t-1)
        #pragma unroll
        for (int ft = 0; ft < 4; ++ft){
            const int c = fb0 + ft * 16 + l15;
            #pragma unroll
            for (int j = 0; j < 4; ++j)
                h0b[(quad * 4 + j) * HP_ + c] = f2bf(h0r[ft][j]);
        }
        __syncthreads();   // h0b (v t) visible

        // ---- layer 1: h0' @ W1ih^T + h1 @ W1hh^T ----
        #pragma unroll
        for (int ft = 0; ft < 4; ++ft){ Tr[ft] = z4; Tz[ft] = z4; Tni[ft] = z4; Tnh[ft] = z4; }
        #pragma unroll
        for (int kc = 0; kc < 8; ++kc){
            const bf16x8 a0 = *(const bf16x8*)&h0b[hoff + kc * 32];
            const bf16x8 a1 = *(const bf16x8*)&h1b[hoff + kc * 32];
            #pragma unroll
            for (int ft = 0; ft < 4; ++ft){
                Tr[ft]  = MFMA16(a0, ldb8g(w1ih + of_hh[ft][0] + kc * 32), Tr[ft]);
                Tr[ft]  = MFMA16(a1, ldb8g(w1hh + of_hh[ft][0] + kc * 32), Tr[ft]);
                Tz[ft]  = MFMA16(a0, ldb8g(w1ih + of_hh[ft][1] + kc * 32), Tz[ft]);
                Tz[ft]  = MFMA16(a1, ldb8g(w1hh + of_hh[ft][1] + kc * 32), Tz[ft]);
                Tni[ft] = MFMA16(a0, ldb8g(w1ih + of_hh[ft][2] + kc * 32), Tni[ft]);
                Tnh[ft] = MFMA16(a1, ldb8g(w1hh + of_hh[ft][2] + kc * 32), Tnh[ft]);
            }
        }
        #pragma unroll
        for (int ft = 0; ft < 4; ++ft){
            const int c = fb0 + ft * 16 + l15;
            #pragma unroll
            for (int j = 0; j < 4; ++j){
                const float rr = sig_(Tr[ft][j] + brz1[c]);
                const float zz = sig_(Tz[ft][j] + brz1[256 + c]);
                const float nn = tanh_(Tni[ft][j] + bni1[c] + rr * (Tnh[ft][j] + bnh1[c]));
                h1r[ft][j] = (1.0f - zz) * nn + zz * h1r[ft][j];
            }
        }
        __syncthreads();   // all waves done reading h1b (v t-1)
        #pragma unroll
        for (int ft = 0; ft < 4; ++ft){
            const int c = fb0 + ft * 16 + l15;
            #pragma unroll
            for (int j = 0; j < 4; ++j)
                h1b[(quad * 4 + j) * HP_ + c] = f2bf(h1r[ft][j]);
        }
        __syncthreads();   // h1b (v t) visible
    }

    #pragma unroll
    for (int ft = 0; ft < 4; ++ft)
        #pragma unroll
        for (int j = 0; j < 4; ++j)
            s_out[(size_t)(m0 + quad * 4 + j) * H_ + fb0 + ft * 16 + l15] = h1r[ft][j];
}

// ---------------------------------------------------------------------------
// Single-step LSTM with zero init state (whh term vanishes), fwd+rev concat.
// grid = 512, block = 256 (dir = tid>>7, unit = tid&127). Gate order i,f,g,o.
// ---------------------------------------------------------------------------
__global__ __launch_bounds__(256) void srt_lstm(
    const float* __restrict__ in,             // (512,256) fp32
    const unsigned short* __restrict__ wf, const unsigned short* __restrict__ bif,
    const unsigned short* __restrict__ bhf,
    const unsigned short* __restrict__ wr, const unsigned short* __restrict__ bir,
    const unsigned short* __restrict__ bhr,
    float* __restrict__ out)                  // (512,256) fp32
{
    __shared__ float sx[256];
    const int b = blockIdx.x, tid = threadIdx.x;
    sx[tid] = in[b * 256 + tid];
    __syncthreads();

    const int dir = tid >> 7, uu = tid & 127;
    const unsigned short* w  = dir ? wr  : wf;
    const unsigned short* bi = dir ? bir : bif;
    const unsigned short* bh = dir ? bhr : bhf;

    const unsigned short* wi = w + (size_t)uu * 256;
    const unsigned short* wg = w + (size_t)(256 + uu) * 256;
    const unsigned short* wo = w + (size_t)(384 + uu) * 256;

    float ai = 0.f, ag = 0.f, ao = 0.f;
    for (int k = 0; k < 256; k += 8){
        const bf16x8 vi = ldb8g(wi + k);
        const bf16x8 vg = ldb8g(wg + k);
        const bf16x8 vo = ldb8g(wo + k);
        #pragma unroll
        for (int j = 0; j < 8; ++j){
            const float s = sx[k + j];
            ai += bf2f((unsigned short)vi[j]) * s;
            ag += bf2f((unsigned short)vg[j]) * s;
            ao += bf2f((unsigned short)vo[j]) * s;
        }
    }
    const float gi = ai + bf2f(bi[uu])       + bf2f(bh[uu]);
    const float gg = ag + bf2f(bi[256 + uu]) + bf2f(bh[256 + uu]);
    const float go = ao + bf2f(bi[384 + uu]) + bf2f(bh[384 + uu]);
    const float c  = sig_(gi) * tanh_(gg);
    out[b * 256 + tid] = sig_(go) * tanh_(c);
}

// ---------------------------------------------------------------------------
// B-spline basis (uniform grid, GRID_SIZE=5, ORDER=3): knots t_p = (p-3)*0.4 - 1.
// ---------------------------------------------------------------------------
__device__ __forceinline__ float knot_(int p){ return (float)(p - 3) * 0.4f - 1.0f; }

__device__ __forceinline__ void bspline8(float xv, float* bb8){
    float bb[11];
    #pragma unroll
    for (int p = 0; p < 11; ++p)
        bb[p] = (xv >= knot_(p) && xv < knot_(p + 1)) ? 1.f : 0.f;
    #pragma unroll
    for (int k = 1; k <= 3; ++k){
        #pragma unroll
        for (int p = 0; p <= 10 - k; ++p){
            const float tp = knot_(p), tpk = knot_(p + k);
            const float tp1 = knot_(p + 1), tpk1 = knot_(p + k + 1);
            bb[p] = (xv - tp) / (tpk - tp) * bb[p] + (tpk1 - xv) / (tpk1 - tp1) * bb[p + 1];
        }
    }
    #pragma unroll
    for (int j = 0; j < 8; ++j) bb8[j] = bb[j];
}

// KAN layer 1: (512,256) -> (512,64). grid=512, block=256.
__global__ __launch_bounds__(256) void srt_kan1(
    const float* __restrict__ in,
    const unsigned short* __restrict__ bw,   // (64,256)
    const unsigned short* __restrict__ sw,   // (64,256,8)
    const unsigned short* __restrict__ sc,   // (64,256)
    float* __restrict__ z)                   // (512,64)
{
    __shared__ float sil[256];
    __shared__ float spl[256][8];
    __shared__ float red[64][4];
    const int b = blockIdx.x, tid = threadIdx.x;

    const float xv = in[b * 256 + tid];
    sil[tid] = xv * sig_(xv);
    float bb[8];
    bspline8(xv, bb);
    #pragma unroll
    for (int j = 0; j < 8; ++j) spl[tid][j] = bb[j];
    __syncthreads();

    const int o = tid >> 2, q = tid & 3;
    float acc = 0.f;
    for (int k = q * 64; k < q * 64 + 64; ++k){
        acc += sil[k] * bf2f(bw[o * 256 + k]);
        float t = 0.f;
        #pragma unroll
        for (int j = 0; j < 8; ++j) t += spl[k][j] * bf2f(sw[(o * 256 + k) * 8 + j]);
        acc += t * bf2f(sc[o * 256 + k]);
    }
    red[o][q] = acc;
    __syncthreads();
    if (tid < 64) z[b * 64 + tid] = red[tid][0] + red[tid][1] + red[tid][2] + red[tid][3];
}

// KAN layer 2: (512,64) -> (512,10), dual-dtype output. grid=512, block=64.
__global__ __launch_bounds__(64) void srt_kan2(
    const float* __restrict__ z,
    const unsigned short* __restrict__ bw,   // (10,64)
    const unsigned short* __restrict__ sw,   // (10,64,8)
    const unsigned short* __restrict__ sc,   // (10,64)
    void* __restrict__ outp,                 // (512,10) bf16 or fp32 per flag
    const unsigned int* __restrict__ flagp)
{
    __shared__ float sil[64];
    __shared__ float spl[64][8];
    const int b = blockIdx.x, tid = threadIdx.x;

    const float xv = z[b * 64 + tid];
    sil[tid] = xv * sig_(xv);
    float bb[8];
    bspline8(xv, bb);
    #pragma unroll
    for (int j = 0; j < 8; ++j) spl[tid][j] = bb[j];
    __syncthreads();

    if (tid < 10){
        float acc = 0.f;
        for (int k = 0; k < 64; ++k){
            acc += sil[k] * bf2f(bw[tid * 64 + k]);
            float t = 0.f;
            #pragma unroll
            for (int j = 0; j < 8; ++j) t += spl[k][j] * bf2f(sw[(tid * 64 + k) * 8 + j]);
            acc += t * bf2f(sc[tid * 64 + k]);
        }
        if (*flagp) ((unsigned short*)outp)[b * 10 + tid] = f2bf(acc);
        else        ((float*)outp)[b * 10 + tid] = acc;
    }
}

extern "C" void kernel_launch(void* const* d_in, const int* in_sizes, int n_in,
                              void* d_out, int out_size, void* d_ws, size_t ws_size,
                              hipStream_t stream)
{
    // ws layout: [flag 16B][s (512,256) f32][o0][o1][zz (512,64) f32][weights bf16 ~2.8MB]
    unsigned int* flag = (unsigned int*)d_ws;
    float* s  = (float*)((char*)d_ws + 16);
    float* o0 = s  + 512 * 256;
    float* o1 = o0 + 512 * 256;
    float* zz = o1 + 512 * 256;
    unsigned short* wb = (unsigned short*)(zz + 512 * 64);

    // staged-weight table: indices into d_in, ws offsets in bf16 elements
    const int idxs[26] = {1,2,3,4,5,6,7,8, 9,11,12, 13,15,16, 17,19,20, 21,23,24,
                          25,26,27, 28,29,30};
    ConvTab ct;
    int off = 0;
    int offs[26];
    for (int j = 0; j < 26; ++j){
        ct.src[j] = d_in[idxs[j]];
        ct.n[j]   = in_sizes[idxs[j]];
        ct.off[j] = off;
        offs[j]   = off;
        off += in_sizes[idxs[j]];
    }
    const unsigned short *w0ih = wb + offs[0],  *w0hh = wb + offs[1];
    const unsigned short *b0ih = wb + offs[2],  *b0hh = wb + offs[3];
    const unsigned short *w1ih = wb + offs[4],  *w1hh = wb + offs[5];
    const unsigned short *b1ih = wb + offs[6],  *b1hh = wb + offs[7];
    const unsigned short *lwih0  = wb + offs[8],  *lbih0  = wb + offs[9],  *lbhh0  = wb + offs[10];
    const unsigned short *lwih0r = wb + offs[11], *lbih0r = wb + offs[12], *lbhh0r = wb + offs[13];
    const unsigned short *lwih1  = wb + offs[14], *lbih1  = wb + offs[15], *lbhh1  = wb + offs[16];
    const unsigned short *lwih1r = wb + offs[17], *lbih1r = wb + offs[18], *lbhh1r = wb + offs[19];
    const unsigned short *k1b = wb + offs[20], *k1s = wb + offs[21], *k1c = wb + offs[22];
    const unsigned short *k2b = wb + offs[23], *k2s = wb + offs[24], *k2c = wb + offs[25];

    srt_detect<<<1, 64, 0, stream>>>((const unsigned int*)d_in[0], flag);
    srt_conv<<<1024, 256, 0, stream>>>(ct, wb, flag);
    srt_gru<<<32, 256, 0, stream>>>(d_in[0], w0ih, w0hh, b0ih, b0hh,
                                    w1ih, w1hh, b1ih, b1hh, s, flag);
    srt_lstm<<<512, 256, 0, stream>>>(s,  lwih0, lbih0, lbhh0, lwih0r, lbih0r, lbhh0r, o0);
    srt_lstm<<<512, 256, 0, stream>>>(o0, lwih1, lbih1, lbhh1, lwih1r, lbih1r, lbhh1r, o1);
    srt_kan1<<<512, 256, 0, stream>>>(o1, k1b, k1s, k1c, zz);
    srt_kan2<<<512, 64, 0, stream>>>(zz, k2b, k2s, k2c, d_out, flag);
}

// Round 3
// 19460.384 us; speedup vs baseline: 1.1476x; 1.1476x over previous
//
#include <hip/hip_runtime.h>
#include <stdint.h>

// SRTKAN: 2-layer GRU scan (T=512) -> 2x bidirectional single-step LSTM -> 2x KAN linear.
// Input dtype (fp32 vs bf16) detected on device (flag in d_ws); weights staged bf16 in d_ws.
// GRU: 32 blocks x 1024 threads (16 waves); wave owns 16 h-features (r,z,n rows); block owns
// 16 batch rows. h state fp32 in registers, bf16 double-buffered in LDS for MFMA A-operands.
// 4 waves/SIMD TLP + low VGPR so weight loads (L2-resident) pipeline.

constexpr int B_  = 512;
constexpr int T_  = 512;
constexpr int IN_ = 128;
constexpr int H_  = 256;
constexpr int HP_ = 264;   // padded bf16 row stride for h tiles in LDS

typedef __attribute__((ext_vector_type(8))) short bf16x8;
typedef __attribute__((ext_vector_type(4))) float f32x4;

#define MFMA16(a, b, c) __builtin_amdgcn_mfma_f32_16x16x32_bf16((a), (b), (c), 0, 0, 0)

__device__ __forceinline__ float bf2f(unsigned short u){
    union { unsigned int i; float f; } v; v.i = ((unsigned int)u) << 16; return v.f;
}
__device__ __forceinline__ unsigned short f2bf(float f){
    union { float f; unsigned int i; } v; v.f = f;
    return (unsigned short)((v.i + 0x7FFFu + ((v.i >> 16) & 1u)) >> 16); // RNE
}
__device__ __forceinline__ float sig_(float x){
    return __builtin_amdgcn_rcpf(1.0f + __expf(-x));
}
__device__ __forceinline__ float tanh_(float x){
    return 1.0f - 2.0f * __builtin_amdgcn_rcpf(1.0f + __expf(2.0f * x));
}
__device__ __forceinline__ bf16x8 ldb8g(const unsigned short* p){ return *(const bf16x8*)p; }

// ---------------------------------------------------------------------------
// dtype detect: low 16 bits of fp32 words of x. bf16-packed -> real bf16 exponents
// (100..140 nearly always for ~N(0,1)); fp32 -> uniform mantissa bits (~16%).
// ---------------------------------------------------------------------------
__global__ void srt_detect(const unsigned int* __restrict__ xw, unsigned int* __restrict__ flag){
    int cnt = 0;
    for (int i = threadIdx.x; i < 1024; i += 64){
        const unsigned int lo = xw[i] & 0xFFFFu;
        const int e = (int)((lo >> 7) & 0xFFu);
        if (e >= 100 && e <= 140) cnt++;
    }
    #pragma unroll
    for (int o = 32; o > 0; o >>= 1) cnt += __shfl_down(cnt, o);
    if (threadIdx.x == 0) *flag = (cnt > 614) ? 1u : 0u;   // 1 = bf16 inputs
}

// ---------------------------------------------------------------------------
// stage all weight/bias tensors as bf16 into d_ws (copy if bf16, RNE-convert if fp32)
// ---------------------------------------------------------------------------
struct ConvTab { const void* src[26]; int n[26]; int off[26]; };

__global__ __launch_bounds__(256) void srt_conv(ConvTab ct, unsigned short* __restrict__ wb,
                                                const unsigned int* __restrict__ flag){
    const bool isb = (*flag != 0);
    const int gsz = gridDim.x * blockDim.x;
    const int gid = blockIdx.x * blockDim.x + threadIdx.x;
    for (int j = 0; j < 26; ++j){
        const int n = ct.n[j];
        unsigned short* o = wb + ct.off[j];
        if (isb){
            const unsigned short* s = (const unsigned short*)ct.src[j];
            for (int i = gid; i < n; i += gsz) o[i] = s[i];
        } else {
            const float* s = (const float*)ct.src[j];
            for (int i = gid; i < n; i += gsz) o[i] = f2bf(s[i]);
        }
    }
}

// ---------------------------------------------------------------------------
// GRU persistent kernel: grid = 32, block = 1024 (16 waves, 4/SIMD).
// Wave wv owns h-features [wv*16, wv*16+16); block owns batch rows [bid*16, +16).
// MFMA 16x16x32 bf16; A[m=l15][k=quad*8+j]; B[k][n=l15]; C/D row=quad*4+j, col=l15.
// h LDS double-buffered: 2 barriers/step.
// ---------------------------------------------------------------------------
__global__ __launch_bounds__(1024, 4) void srt_gru(
    const void* __restrict__ xv,              // (B,T,IN) bf16 OR fp32 per flag
    const unsigned short* __restrict__ w0ih,  // (768,128) bf16 (ws copy)
    const unsigned short* __restrict__ w0hh,  // (768,256)
    const unsigned short* __restrict__ b0ih,  // (768)
    const unsigned short* __restrict__ b0hh,
    const unsigned short* __restrict__ w1ih,  // (768,256)
    const unsigned short* __restrict__ w1hh,  // (768,256)
    const unsigned short* __restrict__ b1ih,
    const unsigned short* __restrict__ b1hh,
    float* __restrict__ s_out,                // (B,H) fp32: final h1
    const unsigned int* __restrict__ flagp)
{
    __shared__ __align__(16) unsigned short h0b[2][16 * HP_];
    __shared__ __align__(16) unsigned short h1b[2][16 * HP_];

    const bool isb = (*flagp != 0);

    const int tid  = threadIdx.x;
    const int lane = tid & 63;
    const int wv   = tid >> 6;     // 0..15
    const int l15  = lane & 15;
    const int quad = lane >> 4;
    const int m0   = blockIdx.x * 16;
    const int c    = wv * 16 + l15;   // owned h-feature (column)

    for (int i = tid; i < 16 * HP_; i += 1024){
        h0b[0][i] = 0; h0b[1][i] = 0; h1b[0][i] = 0; h1b[1][i] = 0;
    }

    // per-lane loop-invariant biases (registers, no LDS)
    const float brz0a = bf2f(b0ih[c])       + bf2f(b0hh[c]);
    const float brz0b = bf2f(b0ih[256 + c]) + bf2f(b0hh[256 + c]);
    const float bni0v = bf2f(b0ih[512 + c]);
    const float bnh0v = bf2f(b0hh[512 + c]);
    const float brz1a = bf2f(b1ih[c])       + bf2f(b1hh[c]);
    const float brz1b = bf2f(b1ih[256 + c]) + bf2f(b1hh[256 + c]);
    const float bni1v = bf2f(b1ih[512 + c]);
    const float bnh1v = bf2f(b1hh[512 + c]);
    __syncthreads();

    float h0r[4] = {0.f, 0.f, 0.f, 0.f};
    float h1r[4] = {0.f, 0.f, 0.f, 0.f};

    // loop-invariant weight row offsets (gate g, feature c)
    int o0ih[3], ohh[3];
    #pragma unroll
    for (int g = 0; g < 3; ++g){
        o0ih[g] = (g * 256 + c) * IN_ + quad * 8;
        ohh[g]  = (g * 256 + c) * H_  + quad * 8;
    }

    const size_t xrow = (size_t)(m0 + l15) * (T_ * IN_) + quad * 8;
    const unsigned short* pxb = (const unsigned short*)xv + xrow;
    const float*          pxf = (const float*)xv + xrow;
    const int hoff = l15 * HP_ + quad * 8;

    const f32x4 z4 = {0.f, 0.f, 0.f, 0.f};

    #pragma unroll 1
    for (int t = 0; t < T_; ++t){
        const int rp = t & 1, wp = rp ^ 1;

        // ---- x_t fragments (dual dtype, uniform branch) ----
        bf16x8 ax[4];
        if (isb){
            #pragma unroll
            for (int kc = 0; kc < 4; ++kc) ax[kc] = ldb8g(pxb + t * IN_ + kc * 32);
        } else {
            #pragma unroll
            for (int kc = 0; kc < 4; ++kc){
                const float* p = pxf + t * IN_ + kc * 32;
                const float4 f0 = *(const float4*)p;
                const float4 f1 = *(const float4*)(p + 4);
                bf16x8 a;
                a[0] = (short)f2bf(f0.x); a[1] = (short)f2bf(f0.y);
                a[2] = (short)f2bf(f0.z); a[3] = (short)f2bf(f0.w);
                a[4] = (short)f2bf(f1.x); a[5] = (short)f2bf(f1.y);
                a[6] = (short)f2bf(f1.z); a[7] = (short)f2bf(f1.w);
                ax[kc] = a;
            }
        }

        f32x4 Tr = z4, Tz = z4, Tni = z4, Tnh = z4;

        // ---- layer 0: x_t @ W0ih^T (K=128) ----
        #pragma unroll
        for (int kc = 0; kc < 4; ++kc){
            Tr  = MFMA16(ax[kc], ldb8g(w0ih + o0ih[0] + kc * 32), Tr);
            Tz  = MFMA16(ax[kc], ldb8g(w0ih + o0ih[1] + kc * 32), Tz);
            Tni = MFMA16(ax[kc], ldb8g(w0ih + o0ih[2] + kc * 32), Tni);
        }
        // ---- layer 0: h0 @ W0hh^T (K=256) ----
        #pragma unroll
        for (int kc = 0; kc < 8; ++kc){
            const bf16x8 a = *(const bf16x8*)&h0b[rp][hoff + kc * 32];
            Tr  = MFMA16(a, ldb8g(w0hh + ohh[0] + kc * 32), Tr);
            Tz  = MFMA16(a, ldb8g(w0hh + ohh[1] + kc * 32), Tz);
            Tnh = MFMA16(a, ldb8g(w0hh + ohh[2] + kc * 32), Tnh);
        }
        // ---- layer 0 gates ----
        #pragma unroll
        for (int j = 0; j < 4; ++j){
            const float rr = sig_(Tr[j] + brz0a);
            const float zz = sig_(Tz[j] + brz0b);
            const float nn = tanh_(Tni[j] + bni0v + rr * (Tnh[j] + bnh0v));
            h0r[j] = (1.0f - zz) * nn + zz * h0r[j];
        }
        #pragma unroll
        for (int j = 0; j < 4; ++j)
            h0b[wp][(quad * 4 + j) * HP_ + c] = f2bf(h0r[j]);
        __syncthreads();   // h0(t) visible

        // ---- layer 1: h0' @ W1ih^T + h1 @ W1hh^T ----
        Tr = z4; Tz = z4; Tni = z4; Tnh = z4;
        #pragma unroll
        for (int kc = 0; kc < 8; ++kc){
            const bf16x8 a0 = *(const bf16x8*)&h0b[wp][hoff + kc * 32];
            const bf16x8 a1 = *(const bf16x8*)&h1b[rp][hoff + kc * 32];
            Tr  = MFMA16(a0, ldb8g(w1ih + ohh[0] + kc * 32), Tr);
            Tr  = MFMA16(a1, ldb8g(w1hh + ohh[0] + kc * 32), Tr);
            Tz  = MFMA16(a0, ldb8g(w1ih + ohh[1] + kc * 32), Tz);
            Tz  = MFMA16(a1, ldb8g(w1hh + ohh[1] + kc * 32), Tz);
            Tni = MFMA16(a0, ldb8g(w1ih + ohh[2] + kc * 32), Tni);
            Tnh = MFMA16(a1, ldb8g(w1hh + ohh[2] + kc * 32), Tnh);
        }
        #pragma unroll
        for (int j = 0; j < 4; ++j){
            const float rr = sig_(Tr[j] + brz1a);
            const float zz = sig_(Tz[j] + brz1b);
            const float nn = tanh_(Tni[j] + bni1v + rr * (Tnh[j] + bnh1v));
            h1r[j] = (1.0f - zz) * nn + zz * h1r[j];
        }
        #pragma unroll
        for (int j = 0; j < 4; ++j)
            h1b[wp][(quad * 4 + j) * HP_ + c] = f2bf(h1r[j]);
        __syncthreads();   // h1(t) visible; rp buffers free for overwrite next step
    }

    #pragma unroll
    for (int j = 0; j < 4; ++j)
        s_out[(size_t)(m0 + quad * 4 + j) * H_ + c] = h1r[j];
}

// ---------------------------------------------------------------------------
// Single-step LSTM with zero init state (whh term vanishes), fwd+rev concat.
// grid = 512, block = 256 (dir = tid>>7, unit = tid&127). Gate order i,f,g,o.
// ---------------------------------------------------------------------------
__global__ __launch_bounds__(256) void srt_lstm(
    const float* __restrict__ in,             // (512,256) fp32
    const unsigned short* __restrict__ wf, const unsigned short* __restrict__ bif,
    const unsigned short* __restrict__ bhf,
    const unsigned short* __restrict__ wr, const unsigned short* __restrict__ bir,
    const unsigned short* __restrict__ bhr,
    float* __restrict__ out)                  // (512,256) fp32
{
    __shared__ float sx[256];
    const int b = blockIdx.x, tid = threadIdx.x;
    sx[tid] = in[b * 256 + tid];
    __syncthreads();

    const int dir = tid >> 7, uu = tid & 127;
    const unsigned short* w  = dir ? wr  : wf;
    const unsigned short* bi = dir ? bir : bif;
    const unsigned short* bh = dir ? bhr : bhf;

    const unsigned short* wi = w + (size_t)uu * 256;
    const unsigned short* wg = w + (size_t)(256 + uu) * 256;
    const unsigned short* wo = w + (size_t)(384 + uu) * 256;

    float ai = 0.f, ag = 0.f, ao = 0.f;
    for (int k = 0; k < 256; k += 8){
        const bf16x8 vi = ldb8g(wi + k);
        const bf16x8 vg = ldb8g(wg + k);
        const bf16x8 vo = ldb8g(wo + k);
        #pragma unroll
        for (int j = 0; j < 8; ++j){
            const float s = sx[k + j];
            ai += bf2f((unsigned short)vi[j]) * s;
            ag += bf2f((unsigned short)vg[j]) * s;
            ao += bf2f((unsigned short)vo[j]) * s;
        }
    }
    const float gi = ai + bf2f(bi[uu])       + bf2f(bh[uu]);
    const float gg = ag + bf2f(bi[256 + uu]) + bf2f(bh[256 + uu]);
    const float go = ao + bf2f(bi[384 + uu]) + bf2f(bh[384 + uu]);
    const float c  = sig_(gi) * tanh_(gg);
    out[b * 256 + tid] = sig_(go) * tanh_(c);
}

// ---------------------------------------------------------------------------
// B-spline basis (uniform grid, GRID_SIZE=5, ORDER=3): knots t_p = (p-3)*0.4 - 1.
// ---------------------------------------------------------------------------
__device__ __forceinline__ float knot_(int p){ return (float)(p - 3) * 0.4f - 1.0f; }

__device__ __forceinline__ void bspline8(float xv, float* bb8){
    float bb[11];
    #pragma unroll
    for (int p = 0; p < 11; ++p)
        bb[p] = (xv >= knot_(p) && xv < knot_(p + 1)) ? 1.f : 0.f;
    #pragma unroll
    for (int k = 1; k <= 3; ++k){
        #pragma unroll
        for (int p = 0; p <= 10 - k; ++p){
            const float tp = knot_(p), tpk = knot_(p + k);
            const float tp1 = knot_(p + 1), tpk1 = knot_(p + k + 1);
            bb[p] = (xv - tp) / (tpk - tp) * bb[p] + (tpk1 - xv) / (tpk1 - tp1) * bb[p + 1];
        }
    }
    #pragma unroll
    for (int j = 0; j < 8; ++j) bb8[j] = bb[j];
}

// KAN layer 1: (512,256) -> (512,64). grid=512, block=256.
__global__ __launch_bounds__(256) void srt_kan1(
    const float* __restrict__ in,
    const unsigned short* __restrict__ bw,   // (64,256)
    const unsigned short* __restrict__ sw,   // (64,256,8)
    const unsigned short* __restrict__ sc,   // (64,256)
    float* __restrict__ z)                   // (512,64)
{
    __shared__ float sil[256];
    __shared__ float spl[256][8];
    __shared__ float red[64][4];
    const int b = blockIdx.x, tid = threadIdx.x;

    const float xv = in[b * 256 + tid];
    sil[tid] = xv * sig_(xv);
    float bb[8];
    bspline8(xv, bb);
    #pragma unroll
    for (int j = 0; j < 8; ++j) spl[tid][j] = bb[j];
    __syncthreads();

    const int o = tid >> 2, q = tid & 3;
    float acc = 0.f;
    for (int k = q * 64; k < q * 64 + 64; ++k){
        acc += sil[k] * bf2f(bw[o * 256 + k]);
        float t = 0.f;
        #pragma unroll
        for (int j = 0; j < 8; ++j) t += spl[k][j] * bf2f(sw[(o * 256 + k) * 8 + j]);
        acc += t * bf2f(sc[o * 256 + k]);
    }
    red[o][q] = acc;
    __syncthreads();
    if (tid < 64) z[b * 64 + tid] = red[tid][0] + red[tid][1] + red[tid][2] + red[tid][3];
}

// KAN layer 2: (512,64) -> (512,10), dual-dtype output. grid=512, block=64.
__global__ __launch_bounds__(64) void srt_kan2(
    const float* __restrict__ z,
    const unsigned short* __restrict__ bw,   // (10,64)
    const unsigned short* __restrict__ sw,   // (10,64,8)
    const unsigned short* __restrict__ sc,   // (10,64)
    void* __restrict__ outp,                 // (512,10) bf16 or fp32 per flag
    const unsigned int* __restrict__ flagp)
{
    __shared__ float sil[64];
    __shared__ float spl[64][8];
    const int b = blockIdx.x, tid = threadIdx.x;

    const float xv = z[b * 64 + tid];
    sil[tid] = xv * sig_(xv);
    float bb[8];
    bspline8(xv, bb);
    #pragma unroll
    for (int j = 0; j < 8; ++j) spl[tid][j] = bb[j];
    __syncthreads();

    if (tid < 10){
        float acc = 0.f;
        for (int k = 0; k < 64; ++k){
            acc += sil[k] * bf2f(bw[tid * 64 + k]);
            float t = 0.f;
            #pragma unroll
            for (int j = 0; j < 8; ++j) t += spl[k][j] * bf2f(sw[(tid * 64 + k) * 8 + j]);
            acc += t * bf2f(sc[tid * 64 + k]);
        }
        if (*flagp) ((unsigned short*)outp)[b * 10 + tid] = f2bf(acc);
        else        ((float*)outp)[b * 10 + tid] = acc;
    }
}

extern "C" void kernel_launch(void* const* d_in, const int* in_sizes, int n_in,
                              void* d_out, int out_size, void* d_ws, size_t ws_size,
                              hipStream_t stream)
{
    // ws layout: [flag 16B][s (512,256) f32][o0][o1][zz (512,64) f32][weights bf16 ~2.8MB]
    unsigned int* flag = (unsigned int*)d_ws;
    float* s  = (float*)((char*)d_ws + 16);
    float* o0 = s  + 512 * 256;
    float* o1 = o0 + 512 * 256;
    float* zz = o1 + 512 * 256;
    unsigned short* wb = (unsigned short*)(zz + 512 * 64);

    const int idxs[26] = {1,2,3,4,5,6,7,8, 9,11,12, 13,15,16, 17,19,20, 21,23,24,
                          25,26,27, 28,29,30};
    ConvTab ct;
    int off = 0;
    int offs[26];
    for (int j = 0; j < 26; ++j){
        ct.src[j] = d_in[idxs[j]];
        ct.n[j]   = in_sizes[idxs[j]];
        ct.off[j] = off;
        offs[j]   = off;
        off += in_sizes[idxs[j]];
    }
    const unsigned short *w0ih = wb + offs[0],  *w0hh = wb + offs[1];
    const unsigned short *b0ih = wb + offs[2],  *b0hh = wb + offs[3];
    const unsigned short *w1ih = wb + offs[4],  *w1hh = wb + offs[5];
    const unsigned short *b1ih = wb + offs[6],  *b1hh = wb + offs[7];
    const unsigned short *lwih0  = wb + offs[8],  *lbih0  = wb + offs[9],  *lbhh0  = wb + offs[10];
    const unsigned short *lwih0r = wb + offs[11], *lbih0r = wb + offs[12], *lbhh0r = wb + offs[13];
    const unsigned short *lwih1  = wb + offs[14], *lbih1  = wb + offs[15], *lbhh1  = wb + offs[16];
    const unsigned short *lwih1r = wb + offs[17], *lbih1r = wb + offs[18], *lbhh1r = wb + offs[19];
    const unsigned short *k1b = wb + offs[20], *k1s = wb + offs[21], *k1c = wb + offs[22];
    const unsigned short *k2b = wb + offs[23], *k2s = wb + offs[24], *k2c = wb + offs[25];

    srt_detect<<<1, 64, 0, stream>>>((const unsigned int*)d_in[0], flag);
    srt_conv<<<1024, 256, 0, stream>>>(ct, wb, flag);
    srt_gru<<<32, 1024, 0, stream>>>(d_in[0], w0ih, w0hh, b0ih, b0hh,
                                     w1ih, w1hh, b1ih, b1hh, s, flag);
    srt_lstm<<<512, 256, 0, stream>>>(s,  lwih0, lbih0, lbhh0, lwih0r, lbih0r, lbhh0r, o0);
    srt_lstm<<<512, 256, 0, stream>>>(o0, lwih1, lbih1, lbhh1, lwih1r, lbih1r, lbhh1r, o1);
    srt_kan1<<<512, 256, 0, stream>>>(o1, k1b, k1s, k1c, zz);
    srt_kan2<<<512, 64, 0, stream>>>(zz, k2b, k2s, k2c, d_out, flag);
}

// Round 4
// 13200.171 us; speedup vs baseline: 1.6918x; 1.4743x over previous
//
#include <hip/hip_runtime.h>
#include <stdint.h>

// SRTKAN: 2-layer GRU scan (T=512) -> 2x bidirectional single-step LSTM -> 2x KAN linear.
// GRU: weights ON-CHIP. 128 blocks = 32 batch-groups x 4 feature-quadrants.
// Per block (256 thr, 4 waves, 1 wave/SIMD, big VGPR budget): its 64-feature weight slice
// lives in registers (w0ih, w1ih, w1hh) + LDS (w0hh, fragment-contiguous). Cross-block
// h exchange per layer per step through global memory with device-scope fences/atomics
// (correct under any XCD mapping). Double-buffered by step parity.

constexpr int B_  = 512;
constexpr int T_  = 512;
constexpr int IN_ = 128;
constexpr int H_  = 256;
constexpr int GR_ = 32;    // batch groups
constexpr int HBE = GR_ * 16 * 256;  // elements per parity plane of h exchange buffer

typedef __attribute__((ext_vector_type(8))) short bf16x8;
typedef __attribute__((ext_vector_type(4))) float f32x4;

#define MFMA16(a, b, c) __builtin_amdgcn_mfma_f32_16x16x32_bf16((a), (b), (c), 0, 0, 0)

__device__ __forceinline__ float bf2f(unsigned short u){
    union { unsigned int i; float f; } v; v.i = ((unsigned int)u) << 16; return v.f;
}
__device__ __forceinline__ unsigned short f2bf(float f){
    union { float f; unsigned int i; } v; v.f = f;
    return (unsigned short)((v.i + 0x7FFFu + ((v.i >> 16) & 1u)) >> 16); // RNE
}
__device__ __forceinline__ float sig_(float x){
    return __builtin_amdgcn_rcpf(1.0f + __expf(-x));
}
__device__ __forceinline__ float tanh_(float x){
    return 1.0f - 2.0f * __builtin_amdgcn_rcpf(1.0f + __expf(2.0f * x));
}
__device__ __forceinline__ bf16x8 ldb8g(const unsigned short* p){ return *(const bf16x8*)p; }

// ---------------------------------------------------------------------------
// dtype detect: low 16 bits of fp32 words of x. bf16-packed -> real bf16 exponents
// (100..140 nearly always for ~N(0,1)); fp32 -> uniform mantissa bits (~16%).
// ---------------------------------------------------------------------------
__global__ void srt_detect(const unsigned int* __restrict__ xw, unsigned int* __restrict__ flag){
    int cnt = 0;
    for (int i = threadIdx.x; i < 1024; i += 64){
        const unsigned int lo = xw[i] & 0xFFFFu;
        const int e = (int)((lo >> 7) & 0xFFu);
        if (e >= 100 && e <= 140) cnt++;
    }
    #pragma unroll
    for (int o = 32; o > 0; o >>= 1) cnt += __shfl_down(cnt, o);
    if (threadIdx.x == 0) *flag = (cnt > 614) ? 1u : 0u;   // 1 = bf16 inputs
}

// ---------------------------------------------------------------------------
// stage all weight/bias tensors as bf16 into d_ws (copy if bf16, RNE-convert if fp32)
// ---------------------------------------------------------------------------
struct ConvTab { const void* src[26]; int n[26]; int off[26]; };

__global__ __launch_bounds__(256) void srt_conv(ConvTab ct, unsigned short* __restrict__ wb,
                                                const unsigned int* __restrict__ flag){
    const bool isb = (*flag != 0);
    const int gsz = gridDim.x * blockDim.x;
    const int gid = blockIdx.x * blockDim.x + threadIdx.x;
    for (int j = 0; j < 26; ++j){
        const int n = ct.n[j];
        unsigned short* o = wb + ct.off[j];
        if (isb){
            const unsigned short* s = (const unsigned short*)ct.src[j];
            for (int i = gid; i < n; i += gsz) o[i] = s[i];
        } else {
            const float* s = (const float*)ct.src[j];
            for (int i = gid; i < n; i += gsz) o[i] = f2bf(s[i]);
        }
    }
}

// zero the exchange sequence counters (d_ws is poisoned before every launch)
__global__ __launch_bounds__(256) void srt_init(unsigned int* __restrict__ seq){
    for (int i = threadIdx.x; i < 2048; i += 256) seq[i] = 0u;
}

// ---------------------------------------------------------------------------
// GRU persistent kernel: grid = 128, block = 256 (4 waves, 1 wave/SIMD).
// Block bid: q = bid>>5 (feature quadrant), g = bid&31 (batch group, rows g*16..+16).
// Wave wv owns features c = q*64 + wv*16 + l15.
// Weights on-chip: w0ih/w1ih/w1hh fragments in VGPRs, w0hh in LDS (frag-contiguous).
// Per-step h exchange via global hb0/hb1 (parity double-buffered) + seq atomics.
// MFMA 16x16x32 bf16; A[m=l15][k=quad*8+j]; B[k][n=l15]; C/D row=quad*4+j, col=l15.
// ---------------------------------------------------------------------------
__global__ __launch_bounds__(256, 1) void srt_gru(
    const void* __restrict__ xv,              // (B,T,IN) bf16 OR fp32 per flag
    const unsigned short* __restrict__ w0ih,  // (768,128) bf16 (ws copy)
    const unsigned short* __restrict__ w0hh,  // (768,256)
    const unsigned short* __restrict__ b0ih,  // (768)
    const unsigned short* __restrict__ b0hh,
    const unsigned short* __restrict__ w1ih,  // (768,256)
    const unsigned short* __restrict__ w1hh,  // (768,256)
    const unsigned short* __restrict__ b1ih,
    const unsigned short* __restrict__ b1hh,
    float* __restrict__ s_out,                // (B,H) fp32: final h1
    const unsigned int* __restrict__ flagp,
    unsigned int* __restrict__ seq0,          // [32 * 32] stride-32 counters
    unsigned int* __restrict__ seq1,
    unsigned short* __restrict__ hb0,         // [2][32][16][256] bf16
    unsigned short* __restrict__ hb1)
{
    // w0hh LDS: [wv][u*8+kc][lane] fragment-contiguous: 4*24*64*8 els = 96 KB
    __shared__ __align__(16) unsigned short w0hhL[4 * 24 * 512];

    const bool isb = (*flagp != 0);

    const int tid  = threadIdx.x;
    const int lane = tid & 63;
    const int wv   = tid >> 6;     // 0..3
    const int l15  = lane & 15;
    const int quad = lane >> 4;
    const int q    = blockIdx.x >> 5;   // feature quadrant
    const int g    = blockIdx.x & 31;   // batch group
    const int m0   = g * 16;
    const int c    = q * 64 + wv * 16 + l15;   // owned h-feature (column)

    // ---- preload weights on-chip (once) ----
    bf16x8 w0ihr[3][4];
    #pragma unroll
    for (int u = 0; u < 3; ++u)
        #pragma unroll
        for (int kc = 0; kc < 4; ++kc)
            w0ihr[u][kc] = ldb8g(w0ih + (u * 256 + c) * IN_ + kc * 32 + quad * 8);

    bf16x8 w1ihr[3][8], w1hhr[3][8];
    #pragma unroll
    for (int u = 0; u < 3; ++u)
        #pragma unroll
        for (int kc = 0; kc < 8; ++kc){
            w1ihr[u][kc] = ldb8g(w1ih + (u * 256 + c) * H_ + kc * 32 + quad * 8);
            w1hhr[u][kc] = ldb8g(w1hh + (u * 256 + c) * H_ + kc * 32 + quad * 8);
        }

    const int wl = wv * 12288 + lane * 8;   // LDS base (elements) for this lane
    #pragma unroll
    for (int u = 0; u < 3; ++u)
        #pragma unroll
        for (int kc = 0; kc < 8; ++kc){
            const bf16x8 f = ldb8g(w0hh + (u * 256 + c) * H_ + kc * 32 + quad * 8);
            *(bf16x8*)&w0hhL[wl + (u * 8 + kc) * 512] = f;
        }

    // per-lane biases
    const float brz0a = bf2f(b0ih[c])       + bf2f(b0hh[c]);
    const float brz0b = bf2f(b0ih[256 + c]) + bf2f(b0hh[256 + c]);
    const float bni0v = bf2f(b0ih[512 + c]);
    const float bnh0v = bf2f(b0hh[512 + c]);
    const float brz1a = bf2f(b1ih[c])       + bf2f(b1hh[c]);
    const float brz1b = bf2f(b1ih[256 + c]) + bf2f(b1hh[256 + c]);
    const float bni1v = bf2f(b1ih[512 + c]);
    const float bnh1v = bf2f(b1hh[512 + c]);
    __syncthreads();

    float h0r[4] = {0.f, 0.f, 0.f, 0.f};
    float h1r[4] = {0.f, 0.f, 0.f, 0.f};

    const size_t xrow = (size_t)(m0 + l15) * (T_ * IN_) + quad * 8;
    const unsigned short* pxb = (const unsigned short*)xv + xrow;
    const float*          pxf = (const float*)xv + xrow;

    // h exchange addressing
    unsigned int* s0 = seq0 + g * 32;
    unsigned int* s1 = seq1 + g * 32;
    const int wslice = m0 * 256;                         // write base (row-major (B,256))
    const int rfrag  = (m0 + l15) * 256 + quad * 8;      // A-frag read base

    const f32x4 z4 = {0.f, 0.f, 0.f, 0.f};
    bf16x8 h0A[8], h1A[8];
    #pragma unroll
    for (int kc = 0; kc < 8; ++kc){
        h0A[kc] = (bf16x8)(short)0;
        h1A[kc] = (bf16x8)(short)0;
    }

    #pragma unroll 1
    for (int t = 0; t < T_; ++t){
        const int par = t & 1;
        const unsigned int tgt = 4u * (unsigned)(t + 1);

        // ---- x_t fragments (dual dtype, uniform branch) ----
        bf16x8 ax[4];
        if (isb){
            #pragma unroll
            for (int kc = 0; kc < 4; ++kc) ax[kc] = ldb8g(pxb + t * IN_ + kc * 32);
        } else {
            #pragma unroll
            for (int kc = 0; kc < 4; ++kc){
                const float* p = pxf + t * IN_ + kc * 32;
                const float4 f0 = *(const float4*)p;
                const float4 f1 = *(const float4*)(p + 4);
                bf16x8 a;
                a[0] = (short)f2bf(f0.x); a[1] = (short)f2bf(f0.y);
                a[2] = (short)f2bf(f0.z); a[3] = (short)f2bf(f0.w);
                a[4] = (short)f2bf(f1.x); a[5] = (short)f2bf(f1.y);
                a[6] = (short)f2bf(f1.z); a[7] = (short)f2bf(f1.w);
                ax[kc] = a;
            }
        }

        // ---- layer 0 ----
        f32x4 Tr = z4, Tz = z4, Tni = z4, Tnh = z4;
        #pragma unroll
        for (int kc = 0; kc < 4; ++kc){
            Tr  = MFMA16(ax[kc], w0ihr[0][kc], Tr);
            Tz  = MFMA16(ax[kc], w0ihr[1][kc], Tz);
            Tni = MFMA16(ax[kc], w0ihr[2][kc], Tni);
        }
        #pragma unroll
        for (int kc = 0; kc < 8; ++kc){
            const bf16x8 a = h0A[kc];
            Tr  = MFMA16(a, *(const bf16x8*)&w0hhL[wl + (0 * 8 + kc) * 512], Tr);
            Tz  = MFMA16(a, *(const bf16x8*)&w0hhL[wl + (1 * 8 + kc) * 512], Tz);
            Tnh = MFMA16(a, *(const bf16x8*)&w0hhL[wl + (2 * 8 + kc) * 512], Tnh);
        }
        #pragma unroll
        for (int j = 0; j < 4; ++j){
            const float rr = sig_(Tr[j] + brz0a);
            const float zz = sig_(Tz[j] + brz0b);
            const float nn = tanh_(Tni[j] + bni0v + rr * (Tnh[j] + bnh0v));
            h0r[j] = (1.0f - zz) * nn + zz * h0r[j];
        }

        // ---- exchange h0 ----
        {
            unsigned short* dst = hb0 + par * HBE + wslice;
            #pragma unroll
            for (int j = 0; j < 4; ++j)
                dst[(quad * 4 + j) * 256 + c] = f2bf(h0r[j]);
            __syncthreads();                       // drains stores (vmcnt 0)
            if (tid == 0){ __threadfence(); atomicAdd(s0, 1u); }
            if (lane == 0){
                while (__hip_atomic_load(s0, __ATOMIC_RELAXED, __HIP_MEMORY_SCOPE_AGENT) < tgt)
                    __builtin_amdgcn_s_sleep(1);
            }
            __threadfence();                       // acquire: invalidate caches
            const unsigned short* src = hb0 + par * HBE + rfrag;
            #pragma unroll
            for (int kc = 0; kc < 8; ++kc) h0A[kc] = ldb8g(src + kc * 32);
        }

        // ---- layer 1 ----
        Tr = z4; Tz = z4; Tni = z4; Tnh = z4;
        #pragma unroll
        for (int kc = 0; kc < 8; ++kc){
            const bf16x8 a0 = h0A[kc];
            const bf16x8 a1 = h1A[kc];
            Tr  = MFMA16(a0, w1ihr[0][kc], Tr);
            Tr  = MFMA16(a1, w1hhr[0][kc], Tr);
            Tz  = MFMA16(a0, w1ihr[1][kc], Tz);
            Tz  = MFMA16(a1, w1hhr[1][kc], Tz);
            Tni = MFMA16(a0, w1ihr[2][kc], Tni);
            Tnh = MFMA16(a1, w1hhr[2][kc], Tnh);
        }
        #pragma unroll
        for (int j = 0; j < 4; ++j){
            const float rr = sig_(Tr[j] + brz1a);
            const float zz = sig_(Tz[j] + brz1b);
            const float nn = tanh_(Tni[j] + bni1v + rr * (Tnh[j] + bnh1v));
            h1r[j] = (1.0f - zz) * nn + zz * h1r[j];
        }

        // ---- exchange h1 ----
        {
            unsigned short* dst = hb1 + par * HBE + wslice;
            #pragma unroll
            for (int j = 0; j < 4; ++j)
                dst[(quad * 4 + j) * 256 + c] = f2bf(h1r[j]);
            __syncthreads();
            if (tid == 0){ __threadfence(); atomicAdd(s1, 1u); }
            if (lane == 0){
                while (__hip_atomic_load(s1, __ATOMIC_RELAXED, __HIP_MEMORY_SCOPE_AGENT) < tgt)
                    __builtin_amdgcn_s_sleep(1);
            }
            __threadfence();
            const unsigned short* src = hb1 + par * HBE + rfrag;
            #pragma unroll
            for (int kc = 0; kc < 8; ++kc) h1A[kc] = ldb8g(src + kc * 32);
        }
    }

    // s = final h1: each block writes its own (16 rows x 64 cols) slice from registers
    #pragma unroll
    for (int j = 0; j < 4; ++j)
        s_out[(size_t)(m0 + quad * 4 + j) * H_ + c] = h1r[j];
}

// ---------------------------------------------------------------------------
// Single-step LSTM with zero init state (whh term vanishes), fwd+rev concat.
// grid = 512, block = 256 (dir = tid>>7, unit = tid&127). Gate order i,f,g,o.
// ---------------------------------------------------------------------------
__global__ __launch_bounds__(256) void srt_lstm(
    const float* __restrict__ in,             // (512,256) fp32
    const unsigned short* __restrict__ wf, const unsigned short* __restrict__ bif,
    const unsigned short* __restrict__ bhf,
    const unsigned short* __restrict__ wr, const unsigned short* __restrict__ bir,
    const unsigned short* __restrict__ bhr,
    float* __restrict__ out)                  // (512,256) fp32
{
    __shared__ float sx[256];
    const int b = blockIdx.x, tid = threadIdx.x;
    sx[tid] = in[b * 256 + tid];
    __syncthreads();

    const int dir = tid >> 7, uu = tid & 127;
    const unsigned short* w  = dir ? wr  : wf;
    const unsigned short* bi = dir ? bir : bif;
    const unsigned short* bh = dir ? bhr : bhf;

    const unsigned short* wi = w + (size_t)uu * 256;
    const unsigned short* wg = w + (size_t)(256 + uu) * 256;
    const unsigned short* wo = w + (size_t)(384 + uu) * 256;

    float ai = 0.f, ag = 0.f, ao = 0.f;
    for (int k = 0; k < 256; k += 8){
        const bf16x8 vi = ldb8g(wi + k);
        const bf16x8 vg = ldb8g(wg + k);
        const bf16x8 vo = ldb8g(wo + k);
        #pragma unroll
        for (int j = 0; j < 8; ++j){
            const float s = sx[k + j];
            ai += bf2f((unsigned short)vi[j]) * s;
            ag += bf2f((unsigned short)vg[j]) * s;
            ao += bf2f((unsigned short)vo[j]) * s;
        }
    }
    const float gi = ai + bf2f(bi[uu])       + bf2f(bh[uu]);
    const float gg = ag + bf2f(bi[256 + uu]) + bf2f(bh[256 + uu]);
    const float go = ao + bf2f(bi[384 + uu]) + bf2f(bh[384 + uu]);
    const float c  = sig_(gi) * tanh_(gg);
    out[b * 256 + tid] = sig_(go) * tanh_(c);
}

// ---------------------------------------------------------------------------
// B-spline basis (uniform grid, GRID_SIZE=5, ORDER=3): knots t_p = (p-3)*0.4 - 1.
// ---------------------------------------------------------------------------
__device__ __forceinline__ float knot_(int p){ return (float)(p - 3) * 0.4f - 1.0f; }

__device__ __forceinline__ void bspline8(float xv, float* bb8){
    float bb[11];
    #pragma unroll
    for (int p = 0; p < 11; ++p)
        bb[p] = (xv >= knot_(p) && xv < knot_(p + 1)) ? 1.f : 0.f;
    #pragma unroll
    for (int k = 1; k <= 3; ++k){
        #pragma unroll
        for (int p = 0; p <= 10 - k; ++p){
            const float tp = knot_(p), tpk = knot_(p + k);
            const float tp1 = knot_(p + 1), tpk1 = knot_(p + k + 1);
            bb[p] = (xv - tp) / (tpk - tp) * bb[p] + (tpk1 - xv) / (tpk1 - tp1) * bb[p + 1];
        }
    }
    #pragma unroll
    for (int j = 0; j < 8; ++j) bb8[j] = bb[j];
}

// KAN layer 1: (512,256) -> (512,64). grid=512, block=256.
__global__ __launch_bounds__(256) void srt_kan1(
    const float* __restrict__ in,
    const unsigned short* __restrict__ bw,   // (64,256)
    const unsigned short* __restrict__ sw,   // (64,256,8)
    const unsigned short* __restrict__ sc,   // (64,256)
    float* __restrict__ z)                   // (512,64)
{
    __shared__ float sil[256];
    __shared__ float spl[256][8];
    __shared__ float red[64][4];
    const int b = blockIdx.x, tid = threadIdx.x;

    const float xv = in[b * 256 + tid];
    sil[tid] = xv * sig_(xv);
    float bb[8];
    bspline8(xv, bb);
    #pragma unroll
    for (int j = 0; j < 8; ++j) spl[tid][j] = bb[j];
    __syncthreads();

    const int o = tid >> 2, qq = tid & 3;
    float acc = 0.f;
    for (int k = qq * 64; k < qq * 64 + 64; ++k){
        acc += sil[k] * bf2f(bw[o * 256 + k]);
        float t = 0.f;
        #pragma unroll
        for (int j = 0; j < 8; ++j) t += spl[k][j] * bf2f(sw[(o * 256 + k) * 8 + j]);
        acc += t * bf2f(sc[o * 256 + k]);
    }
    red[o][qq] = acc;
    __syncthreads();
    if (tid < 64) z[b * 64 + tid] = red[tid][0] + red[tid][1] + red[tid][2] + red[tid][3];
}

// KAN layer 2: (512,64) -> (512,10), dual-dtype output. grid=512, block=64.
__global__ __launch_bounds__(64) void srt_kan2(
    const float* __restrict__ z,
    const unsigned short* __restrict__ bw,   // (10,64)
    const unsigned short* __restrict__ sw,   // (10,64,8)
    const unsigned short* __restrict__ sc,   // (10,64)
    void* __restrict__ outp,                 // (512,10) bf16 or fp32 per flag
    const unsigned int* __restrict__ flagp)
{
    __shared__ float sil[64];
    __shared__ float spl[64][8];
    const int b = blockIdx.x, tid = threadIdx.x;

    const float xv = z[b * 64 + tid];
    sil[tid] = xv * sig_(xv);
    float bb[8];
    bspline8(xv, bb);
    #pragma unroll
    for (int j = 0; j < 8; ++j) spl[tid][j] = bb[j];
    __syncthreads();

    if (tid < 10){
        float acc = 0.f;
        for (int k = 0; k < 64; ++k){
            acc += sil[k] * bf2f(bw[tid * 64 + k]);
            float t = 0.f;
            #pragma unroll
            for (int j = 0; j < 8; ++j) t += spl[k][j] * bf2f(sw[(tid * 64 + k) * 8 + j]);
            acc += t * bf2f(sc[tid * 64 + k]);
        }
        if (*flagp) ((unsigned short*)outp)[b * 10 + tid] = f2bf(acc);
        else        ((float*)outp)[b * 10 + tid] = acc;
    }
}

extern "C" void kernel_launch(void* const* d_in, const int* in_sizes, int n_in,
                              void* d_out, int out_size, void* d_ws, size_t ws_size,
                              hipStream_t stream)
{
    // ws layout: [flag 16B][s][o0][o1][zz][wb bf16][seq0/seq1][hb0][hb1]
    unsigned int* flag = (unsigned int*)d_ws;
    float* s  = (float*)((char*)d_ws + 16);
    float* o0 = s  + 512 * 256;
    float* o1 = o0 + 512 * 256;
    float* zz = o1 + 512 * 256;
    unsigned short* wb = (unsigned short*)(zz + 512 * 64);

    const int idxs[26] = {1,2,3,4,5,6,7,8, 9,11,12, 13,15,16, 17,19,20, 21,23,24,
                          25,26,27, 28,29,30};
    ConvTab ct;
    int off = 0;
    int offs[26];
    for (int j = 0; j < 26; ++j){
        ct.src[j] = d_in[idxs[j]];
        ct.n[j]   = in_sizes[idxs[j]];
        ct.off[j] = off;
        offs[j]   = off;
        off += in_sizes[idxs[j]];
    }
    // exchange buffers after staged weights, 256B-aligned
    uintptr_t p = (uintptr_t)(wb + off);
    p = (p + 255) & ~(uintptr_t)255;
    unsigned int* seq = (unsigned int*)p;           // 2048 u32 (seq0: first 1024, seq1: next)
    unsigned int* seq0 = seq;
    unsigned int* seq1 = seq + 1024;
    unsigned short* hb0 = (unsigned short*)(seq + 2048);   // 2*32*16*256 els = 512 KB
    unsigned short* hb1 = hb0 + 2 * HBE;

    const unsigned short *w0ih = wb + offs[0],  *w0hh = wb + offs[1];
    const unsigned short *b0ih = wb + offs[2],  *b0hh = wb + offs[3];
    const unsigned short *w1ih = wb + offs[4],  *w1hh = wb + offs[5];
    const unsigned short *b1ih = wb + offs[6],  *b1hh = wb + offs[7];
    const unsigned short *lwih0  = wb + offs[8],  *lbih0  = wb + offs[9],  *lbhh0  = wb + offs[10];
    const unsigned short *lwih0r = wb + offs[11], *lbih0r = wb + offs[12], *lbhh0r = wb + offs[13];
    const unsigned short *lwih1  = wb + offs[14], *lbih1  = wb + offs[15], *lbhh1  = wb + offs[16];
    const unsigned short *lwih1r = wb + offs[17], *lbih1r = wb + offs[18], *lbhh1r = wb + offs[19];
    const unsigned short *k1b = wb + offs[20], *k1s = wb + offs[21], *k1c = wb + offs[22];
    const unsigned short *k2b = wb + offs[23], *k2s = wb + offs[24], *k2c = wb + offs[25];

    srt_detect<<<1, 64, 0, stream>>>((const unsigned int*)d_in[0], flag);
    srt_conv<<<1024, 256, 0, stream>>>(ct, wb, flag);
    srt_init<<<1, 256, 0, stream>>>(seq);
    srt_gru<<<128, 256, 0, stream>>>(d_in[0], w0ih, w0hh, b0ih, b0hh,
                                     w1ih, w1hh, b1ih, b1hh, s, flag,
                                     seq0, seq1, hb0, hb1);
    srt_lstm<<<512, 256, 0, stream>>>(s,  lwih0, lbih0, lbhh0, lwih0r, lbih0r, lbhh0r, o0);
    srt_lstm<<<512, 256, 0, stream>>>(o0, lwih1, lbih1, lbhh1, lwih1r, lbih1r, lbhh1r, o1);
    srt_kan1<<<512, 256, 0, stream>>>(o1, k1b, k1s, k1c, zz);
    srt_kan2<<<512, 64, 0, stream>>>(zz, k2b, k2s, k2c, d_out, flag);
}

// Round 5
// 4410.596 us; speedup vs baseline: 5.0634x; 2.9928x over previous
//
#include <hip/hip_runtime.h>
#include <stdint.h>

// SRTKAN: 2-layer GRU scan (T=512) -> 2x bidirectional single-step LSTM -> 2x KAN linear.
// GRU: weights ON-CHIP (regs + LDS), 128 blocks = 32 batch-groups x 4 feature-quadrants.
// ONE cross-block exchange per step ({h0(t), h1(t-1)} together) through the die-level
// Infinity Cache via agent-scope relaxed atomics — NO threadfence (no wbl2/inv) in the
// loop; ordering via the vmcnt(0) drain of __syncthreads + LLC coherence point.

constexpr int B_  = 512;
constexpr int T_  = 512;
constexpr int IN_ = 128;
constexpr int H_  = 256;
constexpr int GR_ = 32;                   // batch groups
constexpr int PL_ = GR_ * 2 * 4096;       // elements per parity plane (h0+h1 per group)

typedef __attribute__((ext_vector_type(8))) short bf16x8;
typedef __attribute__((ext_vector_type(4))) float f32x4;

#define MFMA16(a, b, c) __builtin_amdgcn_mfma_f32_16x16x32_bf16((a), (b), (c), 0, 0, 0)

__device__ __forceinline__ float bf2f(unsigned short u){
    union { unsigned int i; float f; } v; v.i = ((unsigned int)u) << 16; return v.f;
}
__device__ __forceinline__ unsigned short f2bf(float f){
    union { float f; unsigned int i; } v; v.f = f;
    return (unsigned short)((v.i + 0x7FFFu + ((v.i >> 16) & 1u)) >> 16); // RNE
}
__device__ __forceinline__ float sig_(float x){
    return __builtin_amdgcn_rcpf(1.0f + __expf(-x));
}
__device__ __forceinline__ float tanh_(float x){
    return 1.0f - 2.0f * __builtin_amdgcn_rcpf(1.0f + __expf(2.0f * x));
}
__device__ __forceinline__ bf16x8 ldb8g(const unsigned short* p){ return *(const bf16x8*)p; }

union U64x2 { unsigned long long q[2]; bf16x8 v; };

// ---------------------------------------------------------------------------
// dtype detect: low 16 bits of fp32 words of x. bf16-packed -> real bf16 exponents
// (100..140 nearly always for ~N(0,1)); fp32 -> uniform mantissa bits (~16%).
// ---------------------------------------------------------------------------
__global__ void srt_detect(const unsigned int* __restrict__ xw, unsigned int* __restrict__ flag){
    int cnt = 0;
    for (int i = threadIdx.x; i < 1024; i += 64){
        const unsigned int lo = xw[i] & 0xFFFFu;
        const int e = (int)((lo >> 7) & 0xFFu);
        if (e >= 100 && e <= 140) cnt++;
    }
    #pragma unroll
    for (int o = 32; o > 0; o >>= 1) cnt += __shfl_down(cnt, o);
    if (threadIdx.x == 0) *flag = (cnt > 614) ? 1u : 0u;   // 1 = bf16 inputs
}

// ---------------------------------------------------------------------------
// stage all weight/bias tensors as bf16 into d_ws (copy if bf16, RNE-convert if fp32)
// ---------------------------------------------------------------------------
struct ConvTab { const void* src[26]; int n[26]; int off[26]; };

__global__ __launch_bounds__(256) void srt_conv(ConvTab ct, unsigned short* __restrict__ wb,
                                                const unsigned int* __restrict__ flag){
    const bool isb = (*flag != 0);
    const int gsz = gridDim.x * blockDim.x;
    const int gid = blockIdx.x * blockDim.x + threadIdx.x;
    for (int j = 0; j < 26; ++j){
        const int n = ct.n[j];
        unsigned short* o = wb + ct.off[j];
        if (isb){
            const unsigned short* s = (const unsigned short*)ct.src[j];
            for (int i = gid; i < n; i += gsz) o[i] = s[i];
        } else {
            const float* s = (const float*)ct.src[j];
            for (int i = gid; i < n; i += gsz) o[i] = f2bf(s[i]);
        }
    }
}

// zero the exchange sequence counters (d_ws is poisoned before every launch)
__global__ __launch_bounds__(256) void srt_init(unsigned int* __restrict__ seq){
    for (int i = threadIdx.x; i < 1024; i += 256) seq[i] = 0u;
}

// ---------------------------------------------------------------------------
// GRU persistent kernel: grid = 128, block = 256 (4 waves, 1 wave/SIMD).
// Block: q = bid>>5 (feature quadrant), g = bid&31 (batch rows g*16..+16).
// Wave wv owns features c = q*64 + wv*16 + l15. Weights on-chip: w0ih/w1ih/w1hh in
// VGPRs, w0hh in LDS (fragment-contiguous). One LLC exchange per step.
// MFMA 16x16x32 bf16; A[m=l15][k=quad*8+j]; B[k][n=l15]; C/D row=quad*4+j, col=l15.
// ---------------------------------------------------------------------------
__global__ __launch_bounds__(256, 1) void srt_gru(
    const void* __restrict__ xv,              // (B,T,IN) bf16 OR fp32 per flag
    const unsigned short* __restrict__ w0ih,  // (768,128) bf16 (ws copy)
    const unsigned short* __restrict__ w0hh,  // (768,256)
    const unsigned short* __restrict__ b0ih,  // (768)
    const unsigned short* __restrict__ b0hh,
    const unsigned short* __restrict__ w1ih,  // (768,256)
    const unsigned short* __restrict__ w1hh,  // (768,256)
    const unsigned short* __restrict__ b1ih,
    const unsigned short* __restrict__ b1hh,
    float* __restrict__ s_out,                // (B,H) fp32: final h1
    const unsigned int* __restrict__ flagp,
    unsigned int* __restrict__ seq,           // [32 * 32] stride-32 counters
    unsigned short* __restrict__ hb)          // [2][32][2][16][256] bf16
{
    // w0hh LDS: [wv][u*8+kc][lane*8] fragment-contiguous: 4*24*512 els = 96 KB
    __shared__ __align__(16) unsigned short w0hhL[4 * 24 * 512];

    const bool isb = (*flagp != 0);

    const int tid  = threadIdx.x;
    const int lane = tid & 63;
    const int wv   = tid >> 6;     // 0..3
    const int l15  = lane & 15;
    const int quad = lane >> 4;
    const int q    = blockIdx.x >> 5;   // feature quadrant
    const int g    = blockIdx.x & 31;   // batch group
    const int m0   = g * 16;
    const int c    = q * 64 + wv * 16 + l15;   // owned h-feature (column)

    // ---- preload weights on-chip (once) ----
    bf16x8 w0ihr[3][4];
    #pragma unroll
    for (int u = 0; u < 3; ++u)
        #pragma unroll
        for (int kc = 0; kc < 4; ++kc)
            w0ihr[u][kc] = ldb8g(w0ih + (u * 256 + c) * IN_ + kc * 32 + quad * 8);

    bf16x8 w1ihr[3][8], w1hhr[3][8];
    #pragma unroll
    for (int u = 0; u < 3; ++u)
        #pragma unroll
        for (int kc = 0; kc < 8; ++kc){
            w1ihr[u][kc] = ldb8g(w1ih + (u * 256 + c) * H_ + kc * 32 + quad * 8);
            w1hhr[u][kc] = ldb8g(w1hh + (u * 256 + c) * H_ + kc * 32 + quad * 8);
        }

    const int wl = wv * 12288 + lane * 8;   // LDS base (elements) for this lane
    #pragma unroll
    for (int u = 0; u < 3; ++u)
        #pragma unroll
        for (int kc = 0; kc < 8; ++kc){
            const bf16x8 f = ldb8g(w0hh + (u * 256 + c) * H_ + kc * 32 + quad * 8);
            *(bf16x8*)&w0hhL[wl + (u * 8 + kc) * 512] = f;
        }

    // per-lane biases
    const float brz0a = bf2f(b0ih[c])       + bf2f(b0hh[c]);
    const float brz0b = bf2f(b0ih[256 + c]) + bf2f(b0hh[256 + c]);
    const float bni0v = bf2f(b0ih[512 + c]);
    const float bnh0v = bf2f(b0hh[512 + c]);
    const float brz1a = bf2f(b1ih[c])       + bf2f(b1hh[c]);
    const float brz1b = bf2f(b1ih[256 + c]) + bf2f(b1hh[256 + c]);
    const float bni1v = bf2f(b1ih[512 + c]);
    const float bnh1v = bf2f(b1hh[512 + c]);
    __syncthreads();

    float h0r[4] = {0.f, 0.f, 0.f, 0.f};
    float h1r[4] = {0.f, 0.f, 0.f, 0.f};

    const size_t xrow = (size_t)(m0 + l15) * (T_ * IN_) + quad * 8;
    const unsigned short* pxb = (const unsigned short*)xv + xrow;
    const float*          pxf = (const float*)xv + xrow;

    unsigned int* sq = seq + g * 32;
    const int wr_row[4] = {(quad * 4 + 0) * 256 + c, (quad * 4 + 1) * 256 + c,
                           (quad * 4 + 2) * 256 + c, (quad * 4 + 3) * 256 + c};

    const f32x4 z4 = {0.f, 0.f, 0.f, 0.f};
    bf16x8 h0A[8], h1A[8];
    #pragma unroll
    for (int kc = 0; kc < 8; ++kc){
        h0A[kc] = (bf16x8)(short)0;
        h1A[kc] = (bf16x8)(short)0;
    }

    #pragma unroll 1
    for (int t = 0; t < T_; ++t){
        const int par = t & 1;
        const unsigned int tgt = 4u * (unsigned)(t + 1);
        unsigned short* plane = hb + par * PL_ + g * (2 * 4096);   // [h0 4096][h1 4096]

        // ---- publish h1(t-1) slice early (latency hides under L0 compute) ----
        #pragma unroll
        for (int j = 0; j < 4; ++j)
            __hip_atomic_store(&plane[4096 + wr_row[j]], f2bf(h1r[j]),
                               __ATOMIC_RELAXED, __HIP_MEMORY_SCOPE_AGENT);

        // ---- x_t fragments (dual dtype, uniform branch) ----
        bf16x8 ax[4];
        if (isb){
            #pragma unroll
            for (int kc = 0; kc < 4; ++kc) ax[kc] = ldb8g(pxb + t * IN_ + kc * 32);
        } else {
            #pragma unroll
            for (int kc = 0; kc < 4; ++kc){
                const float* p = pxf + t * IN_ + kc * 32;
                const float4 f0 = *(const float4*)p;
                const float4 f1 = *(const float4*)(p + 4);
                bf16x8 a;
                a[0] = (short)f2bf(f0.x); a[1] = (short)f2bf(f0.y);
                a[2] = (short)f2bf(f0.z); a[3] = (short)f2bf(f0.w);
                a[4] = (short)f2bf(f1.x); a[5] = (short)f2bf(f1.y);
                a[6] = (short)f2bf(f1.z); a[7] = (short)f2bf(f1.w);
                ax[kc] = a;
            }
        }

        // ---- layer 0 (h0A = full h0(t-1) from previous exchange) ----
        f32x4 Tr = z4, Tz = z4, Tni = z4, Tnh = z4;
        #pragma unroll
        for (int kc = 0; kc < 4; ++kc){
            Tr  = MFMA16(ax[kc], w0ihr[0][kc], Tr);
            Tz  = MFMA16(ax[kc], w0ihr[1][kc], Tz);
            Tni = MFMA16(ax[kc], w0ihr[2][kc], Tni);
        }
        #pragma unroll
        for (int kc = 0; kc < 8; ++kc){
            const bf16x8 a = h0A[kc];
            Tr  = MFMA16(a, *(const bf16x8*)&w0hhL[wl + (0 * 8 + kc) * 512], Tr);
            Tz  = MFMA16(a, *(const bf16x8*)&w0hhL[wl + (1 * 8 + kc) * 512], Tz);
            Tnh = MFMA16(a, *(const bf16x8*)&w0hhL[wl + (2 * 8 + kc) * 512], Tnh);
        }
        #pragma unroll
        for (int j = 0; j < 4; ++j){
            const float rr = sig_(Tr[j] + brz0a);
            const float zz = sig_(Tz[j] + brz0b);
            const float nn = tanh_(Tni[j] + bni0v + rr * (Tnh[j] + bnh0v));
            h0r[j] = (1.0f - zz) * nn + zz * h0r[j];
        }

        // ---- publish h0(t) slice ----
        #pragma unroll
        for (int j = 0; j < 4; ++j)
            __hip_atomic_store(&plane[wr_row[j]], f2bf(h0r[j]),
                               __ATOMIC_RELAXED, __HIP_MEMORY_SCOPE_AGENT);

        // ---- single sync: stores drained to LLC by barrier's vmcnt(0) ----
        __syncthreads();
        if (tid == 0)
            __hip_atomic_fetch_add(sq, 1u, __ATOMIC_RELAXED, __HIP_MEMORY_SCOPE_AGENT);
        if (lane == 0){
            while (__hip_atomic_load(sq, __ATOMIC_RELAXED, __HIP_MEMORY_SCOPE_AGENT) < tgt)
                __builtin_amdgcn_s_sleep(1);
        }
        __atomic_signal_fence(__ATOMIC_ACQ_REL);

        // ---- read back full h0(t) and h1(t-1) as A-frags (LLC-coherent loads) ----
        {
            const unsigned short* r0 = plane + l15 * 256 + quad * 8;
            #pragma unroll
            for (int kc = 0; kc < 8; ++kc){
                U64x2 u0, u1;
                u0.q[0] = __hip_atomic_load((const unsigned long long*)(r0 + kc * 32),
                                            __ATOMIC_RELAXED, __HIP_MEMORY_SCOPE_AGENT);
                u0.q[1] = __hip_atomic_load((const unsigned long long*)(r0 + kc * 32 + 4),
                                            __ATOMIC_RELAXED, __HIP_MEMORY_SCOPE_AGENT);
                u1.q[0] = __hip_atomic_load((const unsigned long long*)(r0 + 4096 + kc * 32),
                                            __ATOMIC_RELAXED, __HIP_MEMORY_SCOPE_AGENT);
                u1.q[1] = __hip_atomic_load((const unsigned long long*)(r0 + 4096 + kc * 32 + 4),
                                            __ATOMIC_RELAXED, __HIP_MEMORY_SCOPE_AGENT);
                h0A[kc] = u0.v;
                h1A[kc] = u1.v;
            }
        }

        // ---- layer 1: h0(t) @ W1ih^T + h1(t-1) @ W1hh^T ----
        Tr = z4; Tz = z4; Tni = z4; Tnh = z4;
        #pragma unroll
        for (int kc = 0; kc < 8; ++kc){
            const bf16x8 a0 = h0A[kc];
            const bf16x8 a1 = h1A[kc];
            Tr  = MFMA16(a0, w1ihr[0][kc], Tr);
            Tr  = MFMA16(a1, w1hhr[0][kc], Tr);
            Tz  = MFMA16(a0, w1ihr[1][kc], Tz);
            Tz  = MFMA16(a1, w1hhr[1][kc], Tz);
            Tni = MFMA16(a0, w1ihr[2][kc], Tni);
            Tnh = MFMA16(a1, w1hhr[2][kc], Tnh);
        }
        #pragma unroll
        for (int j = 0; j < 4; ++j){
            const float rr = sig_(Tr[j] + brz1a);
            const float zz = sig_(Tz[j] + brz1b);
            const float nn = tanh_(Tni[j] + bni1v + rr * (Tnh[j] + bnh1v));
            h1r[j] = (1.0f - zz) * nn + zz * h1r[j];
        }
    }

    // s = final h1: each block writes its own (16 rows x 64 cols) slice from registers
    #pragma unroll
    for (int j = 0; j < 4; ++j)
        s_out[(size_t)(m0 + quad * 4 + j) * H_ + c] = h1r[j];
}

// ---------------------------------------------------------------------------
// Single-step LSTM with zero init state (whh term vanishes), fwd+rev concat.
// grid = 512, block = 256 (dir = tid>>7, unit = tid&127). Gate order i,f,g,o.
// ---------------------------------------------------------------------------
__global__ __launch_bounds__(256) void srt_lstm(
    const float* __restrict__ in,             // (512,256) fp32
    const unsigned short* __restrict__ wf, const unsigned short* __restrict__ bif,
    const unsigned short* __restrict__ bhf,
    const unsigned short* __restrict__ wr, const unsigned short* __restrict__ bir,
    const unsigned short* __restrict__ bhr,
    float* __restrict__ out)                  // (512,256) fp32
{
    __shared__ float sx[256];
    const int b = blockIdx.x, tid = threadIdx.x;
    sx[tid] = in[b * 256 + tid];
    __syncthreads();

    const int dir = tid >> 7, uu = tid & 127;
    const unsigned short* w  = dir ? wr  : wf;
    const unsigned short* bi = dir ? bir : bif;
    const unsigned short* bh = dir ? bhr : bhf;

    const unsigned short* wi = w + (size_t)uu * 256;
    const unsigned short* wg = w + (size_t)(256 + uu) * 256;
    const unsigned short* wo = w + (size_t)(384 + uu) * 256;

    float ai = 0.f, ag = 0.f, ao = 0.f;
    for (int k = 0; k < 256; k += 8){
        const bf16x8 vi = ldb8g(wi + k);
        const bf16x8 vg = ldb8g(wg + k);
        const bf16x8 vo = ldb8g(wo + k);
        #pragma unroll
        for (int j = 0; j < 8; ++j){
            const float s = sx[k + j];
            ai += bf2f((unsigned short)vi[j]) * s;
            ag += bf2f((unsigned short)vg[j]) * s;
            ao += bf2f((unsigned short)vo[j]) * s;
        }
    }
    const float gi = ai + bf2f(bi[uu])       + bf2f(bh[uu]);
    const float gg = ag + bf2f(bi[256 + uu]) + bf2f(bh[256 + uu]);
    const float go = ao + bf2f(bi[384 + uu]) + bf2f(bh[384 + uu]);
    const float c  = sig_(gi) * tanh_(gg);
    out[b * 256 + tid] = sig_(go) * tanh_(c);
}

// ---------------------------------------------------------------------------
// B-spline basis (uniform grid, GRID_SIZE=5, ORDER=3): knots t_p = (p-3)*0.4 - 1.
// ---------------------------------------------------------------------------
__device__ __forceinline__ float knot_(int p){ return (float)(p - 3) * 0.4f - 1.0f; }

__device__ __forceinline__ void bspline8(float xv, float* bb8){
    float bb[11];
    #pragma unroll
    for (int p = 0; p < 11; ++p)
        bb[p] = (xv >= knot_(p) && xv < knot_(p + 1)) ? 1.f : 0.f;
    #pragma unroll
    for (int k = 1; k <= 3; ++k){
        #pragma unroll
        for (int p = 0; p <= 10 - k; ++p){
            const float tp = knot_(p), tpk = knot_(p + k);
            const float tp1 = knot_(p + 1), tpk1 = knot_(p + k + 1);
            bb[p] = (xv - tp) / (tpk - tp) * bb[p] + (tpk1 - xv) / (tpk1 - tp1) * bb[p + 1];
        }
    }
    #pragma unroll
    for (int j = 0; j < 8; ++j) bb8[j] = bb[j];
}

// KAN layer 1: (512,256) -> (512,64). grid=512, block=256.
__global__ __launch_bounds__(256) void srt_kan1(
    const float* __restrict__ in,
    const unsigned short* __restrict__ bw,   // (64,256)
    const unsigned short* __restrict__ sw,   // (64,256,8)
    const unsigned short* __restrict__ sc,   // (64,256)
    float* __restrict__ z)                   // (512,64)
{
    __shared__ float sil[256];
    __shared__ float spl[256][8];
    __shared__ float red[64][4];
    const int b = blockIdx.x, tid = threadIdx.x;

    const float xv = in[b * 256 + tid];
    sil[tid] = xv * sig_(xv);
    float bb[8];
    bspline8(xv, bb);
    #pragma unroll
    for (int j = 0; j < 8; ++j) spl[tid][j] = bb[j];
    __syncthreads();

    const int o = tid >> 2, qq = tid & 3;
    float acc = 0.f;
    for (int k = qq * 64; k < qq * 64 + 64; ++k){
        acc += sil[k] * bf2f(bw[o * 256 + k]);
        float t = 0.f;
        #pragma unroll
        for (int j = 0; j < 8; ++j) t += spl[k][j] * bf2f(sw[(o * 256 + k) * 8 + j]);
        acc += t * bf2f(sc[o * 256 + k]);
    }
    red[o][qq] = acc;
    __syncthreads();
    if (tid < 64) z[b * 64 + tid] = red[tid][0] + red[tid][1] + red[tid][2] + red[tid][3];
}

// KAN layer 2: (512,64) -> (512,10), dual-dtype output. grid=512, block=64.
__global__ __launch_bounds__(64) void srt_kan2(
    const float* __restrict__ z,
    const unsigned short* __restrict__ bw,   // (10,64)
    const unsigned short* __restrict__ sw,   // (10,64,8)
    const unsigned short* __restrict__ sc,   // (10,64)
    void* __restrict__ outp,                 // (512,10) bf16 or fp32 per flag
    const unsigned int* __restrict__ flagp)
{
    __shared__ float sil[64];
    __shared__ float spl[64][8];
    const int b = blockIdx.x, tid = threadIdx.x;

    const float xv = z[b * 64 + tid];
    sil[tid] = xv * sig_(xv);
    float bb[8];
    bspline8(xv, bb);
    #pragma unroll
    for (int j = 0; j < 8; ++j) spl[tid][j] = bb[j];
    __syncthreads();

    if (tid < 10){
        float acc = 0.f;
        for (int k = 0; k < 64; ++k){
            acc += sil[k] * bf2f(bw[tid * 64 + k]);
            float t = 0.f;
            #pragma unroll
            for (int j = 0; j < 8; ++j) t += spl[k][j] * bf2f(sw[(tid * 64 + k) * 8 + j]);
            acc += t * bf2f(sc[tid * 64 + k]);
        }
        if (*flagp) ((unsigned short*)outp)[b * 10 + tid] = f2bf(acc);
        else        ((float*)outp)[b * 10 + tid] = acc;
    }
}

extern "C" void kernel_launch(void* const* d_in, const int* in_sizes, int n_in,
                              void* d_out, int out_size, void* d_ws, size_t ws_size,
                              hipStream_t stream)
{
    // ws layout: [flag 16B][s][o0][o1][zz][wb bf16][seq][hb]
    unsigned int* flag = (unsigned int*)d_ws;
    float* s  = (float*)((char*)d_ws + 16);
    float* o0 = s  + 512 * 256;
    float* o1 = o0 + 512 * 256;
    float* zz = o1 + 512 * 256;
    unsigned short* wb = (unsigned short*)(zz + 512 * 64);

    const int idxs[26] = {1,2,3,4,5,6,7,8, 9,11,12, 13,15,16, 17,19,20, 21,23,24,
                          25,26,27, 28,29,30};
    ConvTab ct;
    int off = 0;
    int offs[26];
    for (int j = 0; j < 26; ++j){
        ct.src[j] = d_in[idxs[j]];
        ct.n[j]   = in_sizes[idxs[j]];
        ct.off[j] = off;
        offs[j]   = off;
        off += in_sizes[idxs[j]];
    }
    // exchange buffers after staged weights, 256B-aligned
    uintptr_t p = (uintptr_t)(wb + off);
    p = (p + 255) & ~(uintptr_t)255;
    unsigned int* seq = (unsigned int*)p;                 // 1024 u32 (stride 32 per group)
    unsigned short* hb = (unsigned short*)(seq + 1024);   // 2*32*2*4096 els = 1 MB

    const unsigned short *w0ih = wb + offs[0],  *w0hh = wb + offs[1];
    const unsigned short *b0ih = wb + offs[2],  *b0hh = wb + offs[3];
    const unsigned short *w1ih = wb + offs[4],  *w1hh = wb + offs[5];
    const unsigned short *b1ih = wb + offs[6],  *b1hh = wb + offs[7];
    const unsigned short *lwih0  = wb + offs[8],  *lbih0  = wb + offs[9],  *lbhh0  = wb + offs[10];
    const unsigned short *lwih0r = wb + offs[11], *lbih0r = wb + offs[12], *lbhh0r = wb + offs[13];
    const unsigned short *lwih1  = wb + offs[14], *lbih1  = wb + offs[15], *lbhh1  = wb + offs[16];
    const unsigned short *lwih1r = wb + offs[17], *lbih1r = wb + offs[18], *lbhh1r = wb + offs[19];
    const unsigned short *k1b = wb + offs[20], *k1s = wb + offs[21], *k1c = wb + offs[22];
    const unsigned short *k2b = wb + offs[23], *k2s = wb + offs[24], *k2c = wb + offs[25];

    srt_detect<<<1, 64, 0, stream>>>((const unsigned int*)d_in[0], flag);
    srt_conv<<<1024, 256, 0, stream>>>(ct, wb, flag);
    srt_init<<<1, 256, 0, stream>>>(seq);
    srt_gru<<<128, 256, 0, stream>>>(d_in[0], w0ih, w0hh, b0ih, b0hh,
                                     w1ih, w1hh, b1ih, b1hh, s, flag, seq, hb);
    srt_lstm<<<512, 256, 0, stream>>>(s,  lwih0, lbih0, lbhh0, lwih0r, lbih0r, lbhh0r, o0);
    srt_lstm<<<512, 256, 0, stream>>>(o0, lwih1, lbih1, lbhh1, lwih1r, lbih1r, lbhh1r, o1);
    srt_kan1<<<512, 256, 0, stream>>>(o1, k1b, k1s, k1c, zz);
    srt_kan2<<<512, 64, 0, stream>>>(zz, k2b, k2s, k2c, d_out, flag);
}